// Round 11
// baseline (46191.815 us; speedup 1.0000x reference)
//
#include <hip/hip_runtime.h>
#include <hip/hip_fp16.h>
#include <stdint.h>

// ---------------- problem constants ----------------
#define TT     8000
#define TLOW   800
#define TMEL   80
#define NMEL   80
#define NB     8
#define HD     512
#define LC     20
#define NPRE   256
#define NSS    30

// h broadcast buffers: slot s holds h[s-1]; slot 0 = zeros. per slot: 8 batches x 128 u64 (512 fp16)
#define HB_SLOTS (TT + 1)
#define HB_U64   ((size_t)HB_SLOTS * 8 * 128)
#define HB_BYTES (HB_U64 * 8)
#define CONV_BYTES   ((size_t)NB * TLOW * LC * 4)
#define INTERP_BYTES ((size_t)NB * TT * 4)
#define PREW16_BYTES ((size_t)NPRE * HD * 2)
#define OUTW16_BYTES ((size_t)NSS * NPRE * 2)

typedef __attribute__((ext_vector_type(8))) _Float16 half8;
typedef __attribute__((ext_vector_type(4))) float f32x4;

static __device__ __forceinline__ unsigned short f2h_bits(float f) {
    union { _Float16 h; unsigned short u; } c; c.h = (_Float16)f; return c.u;  // RNE
}
static __device__ __forceinline__ float sigf(float x) {
    x = fminf(30.f, fmaxf(-30.f, x));
    return 1.f / (1.f + __expf(-x));
}
static __device__ __forceinline__ float tanhf_(float x) {
    x = fminf(15.f, fmaxf(-15.f, x));
    float e = __expf(2.f * x);
    return (e - 1.f) / (e + 1.f);
}
static __device__ __forceinline__ half8 mkfrag(unsigned long long a, unsigned long long b) {
    union { unsigned long long q[2]; half8 v; } u; u.q[0] = a; u.q[1] = b; return u.v;
}
static __device__ __forceinline__ f32x4 mfma(half8 a, half8 b, f32x4 c) {
    return __builtin_amdgcn_mfma_f32_16x16x32_f16(a, b, c, 0, 0, 0);
}

// ---------------- data-carrying whole-h poll (32 u64/lane = full 512-h B-frags) ----
static __device__ __forceinline__ void issue32(const unsigned long long* __restrict__ slot,
                                               int bb, int lk, unsigned long long* __restrict__ q)
{
    const unsigned long long* base = slot + (size_t)bb * 128 + lk * 2;
    #pragma unroll
    for (int kt = 0; kt < 16; kt++) {
        q[2 * kt]     = __hip_atomic_load(base + kt * 8,     __ATOMIC_RELAXED, __HIP_MEMORY_SCOPE_AGENT);
        q[2 * kt + 1] = __hip_atomic_load(base + kt * 8 + 1, __ATOMIC_RELAXED, __HIP_MEMORY_SCOPE_AGENT);
    }
}
static __device__ __forceinline__ bool good32(const unsigned long long* __restrict__ q)
{
    bool bad = false;
    #pragma unroll
    for (int k = 0; k < 32; k++) {
        unsigned int lo = (unsigned int)q[k], hi = (unsigned int)(q[k] >> 32);
        bad |= (lo == 0xFFFFFFFFu) | (hi == 0xFFFFFFFFu);
    }
    return !__any(bad);
}

// ---------------- K0: convert pre_w / out_w to fp16 ----------------
__global__ __launch_bounds__(256) void k_prep(
    const float* __restrict__ pre_w, const float* __restrict__ out_w,
    unsigned short* __restrict__ prew16, unsigned short* __restrict__ outw16)
{
    int i = blockIdx.x * 256 + threadIdx.x;
    if (i < NPRE * HD) prew16[i] = f2h_bits(pre_w[i]);
    if (i < NSS * NPRE) outw16[i] = f2h_bits(out_w[i]);
}

// ---------------- K1: conv stack + linear interp (all f32) ----------------
#define CHW 218   // 200 + 2*9 halo (3 conv layers x pad 3)
__global__ __launch_bounds__(256) void k_conv(
    const float* __restrict__ xlow,
    const float* __restrict__ w0, const float* __restrict__ cb0,
    const float* __restrict__ w1, const float* __restrict__ cb1,
    const float* __restrict__ w2, const float* __restrict__ cb2,
    float* __restrict__ convout, float* __restrict__ interp)
{
    int blk = blockIdx.x; int b = blk >> 2; int ch = blk & 3; int cb = ch * 200;
    int tid = threadIdx.x;
    __shared__ float xr[224];
    __shared__ float w0l[LC * 7], w1l[LC * LC * 7], w2l[LC * LC * 7];
    __shared__ float b0l[LC], b1l[LC], b2l[LC];
    __shared__ float h0[LC][CHW], h1[LC][CHW];

    for (int i = tid; i < LC * 7; i += 256) w0l[i] = w0[i];
    for (int i = tid; i < LC * LC * 7; i += 256) { w1l[i] = w1[i]; w2l[i] = w2[i]; }
    for (int i = tid; i < LC; i += 256) { b0l[i] = cb0[i]; b1l[i] = cb1[i]; b2l[i] = cb2[i]; }
    for (int i = tid; i < 224; i += 256) {
        int g = cb - 12 + i;
        xr[i] = (g >= 0 && g < TLOW) ? xlow[b * TLOW + g] : 0.f;
    }
    __syncthreads();
    for (int i = tid; i < LC * CHW; i += 256) {
        int c = i / CHW, s = i - c * CHW;
        int tg = cb - 9 + s;
        float a = b0l[c];
        #pragma unroll
        for (int j = 0; j < 7; j++) a += w0l[c * 7 + j] * xr[s + j];
        h0[c][s] = (tg >= 0 && tg < TLOW) ? tanhf_(a) : 0.f;
    }
    __syncthreads();
    for (int i = tid; i < LC * CHW; i += 256) {
        int c = i / CHW, s = i - c * CHW;
        int tg = cb - 9 + s;
        float a = b1l[c];
        for (int ci = 0; ci < LC; ci++) {
            #pragma unroll
            for (int j = 0; j < 7; j++) {
                int ss = s + j - 3;
                float hv = (ss >= 0 && ss < CHW) ? h0[ci][ss] : 0.f;
                a += w1l[(c * LC + ci) * 7 + j] * hv;
            }
        }
        h1[c][s] = (tg >= 0 && tg < TLOW) ? tanhf_(a) : 0.f;
    }
    __syncthreads();
    for (int i = tid; i < LC * 200; i += 256) {
        int c = i / 200, t0 = i - c * 200; int s = t0 + 9;
        float a = b2l[c];
        for (int ci = 0; ci < LC; ci++) {
            #pragma unroll
            for (int j = 0; j < 7; j++) a += w2l[(c * LC + ci) * 7 + j] * h1[ci][s + j - 3];
        }
        convout[((size_t)b * TLOW + cb + t0) * LC + c] = tanhf_(a);
    }
    for (int i = tid; i < 2000; i += 256) {
        int t = cb * 10 + i;
        float src = ((float)t + 0.5f) * 0.1f - 0.5f;
        src = fminf(fmaxf(src, 0.f), (float)(TLOW - 1));
        int i0 = (int)floorf(src); int i1 = (i0 + 1 < TLOW) ? i0 + 1 : TLOW - 1;
        float w = src - (float)i0;
        interp[(size_t)b * TT + t] = xlow[b * TLOW + i0] * (1.f - w) + xlow[b * TLOW + i1] * w;
    }
}

// ---------------- K2: persistent GRU recurrence — single-wave autonomous blocks ----
// grid: 64 blocks x 64 threads (1 wave). blocks 0-31 = layer0 (16 h-rows each),
// 32-63 = layer1. NO barriers in the step loop: the wave polls its B-operands
// straight into registers (data-carrying), runs 3 gate-tiles of MFMAs (A: x-part
// weights in VGPR, h-part weights in 48KB swizzled LDS), computes the GRU cell
// IN-LANE (C layout puts r/z/n for (row,batch) in the same lane), publishes 1 u64.
__global__ __launch_bounds__(64, 1) void k_rnn(
    const float* __restrict__ mel, const float* __restrict__ gsx,
    const float* __restrict__ convout, const float* __restrict__ interp,
    const float* __restrict__ wih0, const float* __restrict__ whh0,
    const float* __restrict__ bih0, const float* __restrict__ bhh0,
    const float* __restrict__ wih1, const float* __restrict__ whh1,
    const float* __restrict__ bih1, const float* __restrict__ bhh1,
    unsigned long long* __restrict__ h0buf, unsigned long long* __restrict__ h1buf)
{
    const int lane = threadIdx.x;
    const int lm = lane & 15, lk = lane >> 4;
    const int bb = lm & 7;
    const bool isL0 = (blockIdx.x < 32);
    const int cbid = isL0 ? blockIdx.x : (blockIdx.x - 32);
    const int cb = cbid * 16;                  // h-row chunk base

    __shared__ unsigned short wlds[48 * 512];  // h-part weights, XOR-swizzled (48KB)
    __shared__ __align__(16) unsigned short xvec[16][136];  // L0 input vector

    // h-part weights -> LDS (row = g*16+rr, K=512), swizzle byte ^= (row&7)<<4
    {
        const float* wsrc = isL0 ? whh0 : whh1;
        for (int idx = lane; idx < 48 * 512; idx += 64) {
            int row = idx >> 9, k = idx & 511;
            int grow = (row >> 4) * 512 + cb + (row & 15);
            int byte = row * 1024 + ((k * 2) ^ ((row & 7) << 4));
            *(unsigned short*)((char*)wlds + byte) = f2h_bits(wsrc[(size_t)grow * 512 + k]);
        }
    }
    for (int i = lane; i < 16 * 136; i += 64) (&xvec[0][0])[i] = 0;

    // x-part weights -> VGPR. L0: 3 gates x 4 kts (K=128, cols>=102 zero).
    // L1: 3 gates x 16 kts (wih1, K=512 consuming h0).
    half8 wx[3][16];
    #pragma unroll
    for (int g = 0; g < 3; g++) {
        int grow = g * 512 + cb + lm;
        if (isL0) {
            #pragma unroll
            for (int kt = 0; kt < 4; kt++)
                #pragma unroll
                for (int j = 0; j < 8; j++) {
                    int k = kt * 32 + lk * 8 + j;
                    wx[g][kt][j] = (k < 102) ? (_Float16)wih0[(size_t)grow * 102 + k] : (_Float16)0.f;
                }
        } else {
            #pragma unroll
            for (int kt = 0; kt < 16; kt++)
                #pragma unroll
                for (int j = 0; j < 8; j++)
                    wx[g][kt][j] = (_Float16)wih1[(size_t)grow * 512 + kt * 32 + lk * 8 + j];
        }
    }

    // per-lane cell state: rows cb+lk*4+e, batch lm (lanes lm>=8 mirror, not published)
    const int rbase = cb + lk * 4;
    float br[4], bz[4], bin_[4], bhn_[4], hr[4];
    {
        const float* bi = isL0 ? bih0 : bih1;
        const float* bh = isL0 ? bhh0 : bhh1;
        #pragma unroll
        for (int e = 0; e < 4; e++) {
            br[e]   = bi[rbase + e] + bh[rbase + e];
            bz[e]   = bi[512 + rbase + e] + bh[512 + rbase + e];
            bin_[e] = bi[1024 + rbase + e];
            bhn_[e] = bh[1024 + rbase + e];
            hr[e] = 0.f;
        }
    }
    __syncthreads();   // once: LDS weights + xvec zeros visible (single wave, cheap)

    // publish h[-1] = 0 for own rows (slot 0)
    {
        unsigned long long* buf = isL0 ? h0buf : h1buf;
        if (lm < 8)
            __hip_atomic_store(buf + (size_t)lm * 128 + (cb >> 2) + lk, 0ull,
                               __ATOMIC_RELAXED, __HIP_MEMORY_SCOPE_AGENT);
    }

    #define LDSA(g, kt) (*(const half8*)((const char*)wlds + ((g) * 16 + lm) * 1024 \
                          + ((((kt) * 64) + lk * 16) ^ ((lm & 7) << 4))))

    if (isL0) {
        for (int t = 0; t < TT; t++) {
            // x(t) gather: issue early, lands during the h0 poll spin
            float pf[13];
            #pragma unroll
            for (int u = 0; u < 13; u++) {
                int e = lane + 64 * u; float v = 0.f;
                if (e < 816) {
                    int b2 = e / 102, k = e - 102 * b2;
                    if (k < 80)       v = mel[((size_t)b2 * TMEL + t / 100) * NMEL + k];
                    else if (k < 100) v = convout[((size_t)b2 * TLOW + t / 10) * LC + (k - 80)];
                    else if (k == 100) v = interp[(size_t)b2 * TT + t];
                    else               v = gsx[(size_t)b2 * TT + t];
                }
                pf[u] = v;
            }
            // data-carrying poll of h0[t-1] (slot t)
            unsigned long long q[32];
            issue32(h0buf + (size_t)t * 1024, bb, lk, q);
            while (!good32(q)) { __builtin_amdgcn_s_sleep(1); issue32(h0buf + (size_t)t * 1024, bb, lk, q); }

            // xvec write + frag reads (wave-internal LDS ordering, no barrier)
            #pragma unroll
            for (int u = 0; u < 13; u++) {
                int e = lane + 64 * u;
                if (e < 816) { int b2 = e / 102, k = e - 102 * b2; xvec[b2][k] = f2h_bits(pf[u]); }
            }
            f32x4 aR = {0.f,0.f,0.f,0.f}, aZ = {0.f,0.f,0.f,0.f};
            f32x4 aNx = {0.f,0.f,0.f,0.f}, aNh = {0.f,0.f,0.f,0.f};
            #pragma unroll
            for (int kt = 0; kt < 4; kt++) {
                half8 xf = *(const half8*)&xvec[lm][kt * 32 + lk * 8];
                aR  = mfma(wx[0][kt], xf, aR);
                aZ  = mfma(wx[1][kt], xf, aZ);
                aNx = mfma(wx[2][kt], xf, aNx);
            }
            #pragma unroll
            for (int kt = 0; kt < 16; kt++) {
                half8 hb = mkfrag(q[2 * kt], q[2 * kt + 1]);
                aR  = mfma(LDSA(0, kt), hb, aR);
                aZ  = mfma(LDSA(1, kt), hb, aZ);
                aNh = mfma(LDSA(2, kt), hb, aNh);
            }
            // in-lane GRU cell + publish
            unsigned long long pk = 0ull;
            #pragma unroll
            for (int e = 0; e < 4; e++) {
                float r = sigf(aR[e] + br[e]);
                float z = sigf(aZ[e] + bz[e]);
                float n = tanhf_(aNx[e] + bin_[e] + r * (aNh[e] + bhn_[e]));
                hr[e] = (1.f - z) * n + z * hr[e];
                pk |= ((unsigned long long)f2h_bits(hr[e])) << (16 * e);
            }
            if (lm < 8)
                __hip_atomic_store(h0buf + (size_t)(t + 1) * 1024 + (size_t)lm * 128 + (cb >> 2) + lk,
                                   pk, __ATOMIC_RELAXED, __HIP_MEMORY_SCOPE_AGENT);
        }
    } else {
        for (int t = 0; t < TT; t++) {
            // poll h0[t] (slot t+1; L0 runs ahead)
            unsigned long long q0[32];
            issue32(h0buf + (size_t)(t + 1) * 1024, bb, lk, q0);
            while (!good32(q0)) { __builtin_amdgcn_s_sleep(1); issue32(h0buf + (size_t)(t + 1) * 1024, bb, lk, q0); }

            // pre-issue the h1 edge loads; x-MFMAs hide their flight
            unsigned long long q1[32];
            issue32(h1buf + (size_t)t * 1024, bb, lk, q1);

            f32x4 aR = {0.f,0.f,0.f,0.f}, aZ = {0.f,0.f,0.f,0.f};
            f32x4 aNx = {0.f,0.f,0.f,0.f}, aNh = {0.f,0.f,0.f,0.f};
            #pragma unroll
            for (int kt = 0; kt < 16; kt++) {
                half8 hb = mkfrag(q0[2 * kt], q0[2 * kt + 1]);
                aR  = mfma(wx[0][kt], hb, aR);
                aZ  = mfma(wx[1][kt], hb, aZ);
                aNx = mfma(wx[2][kt], hb, aNx);
            }
            while (!good32(q1)) { __builtin_amdgcn_s_sleep(1); issue32(h1buf + (size_t)t * 1024, bb, lk, q1); }
            #pragma unroll
            for (int kt = 0; kt < 16; kt++) {
                half8 hb = mkfrag(q1[2 * kt], q1[2 * kt + 1]);
                aR  = mfma(LDSA(0, kt), hb, aR);
                aZ  = mfma(LDSA(1, kt), hb, aZ);
                aNh = mfma(LDSA(2, kt), hb, aNh);
            }
            unsigned long long pk = 0ull;
            #pragma unroll
            for (int e = 0; e < 4; e++) {
                float r = sigf(aR[e] + br[e]);
                float z = sigf(aZ[e] + bz[e]);
                float n = tanhf_(aNx[e] + bin_[e] + r * (aNh[e] + bhn_[e]));
                hr[e] = (1.f - z) * n + z * hr[e];
                pk |= ((unsigned long long)f2h_bits(hr[e])) << (16 * e);
            }
            if (lm < 8)
                __hip_atomic_store(h1buf + (size_t)(t + 1) * 1024 + (size_t)lm * 128 + (cb >> 2) + lk,
                                   pk, __ATOMIC_RELAXED, __HIP_MEMORY_SCOPE_AGENT);
        }
    }
    #undef LDSA
}

// ---------------- K3: fused head ----------------
__global__ __launch_bounds__(256) void k_final(
    const unsigned long long* __restrict__ h1buf,
    const unsigned short* __restrict__ prew16, const float* __restrict__ pre_b,
    const unsigned short* __restrict__ outw16, const float* __restrict__ out_b,
    float* __restrict__ out)
{
    int blk = blockIdx.x; int b = blk / 125; int tb = (blk - b * 125) * 64;
    int tid = threadIdx.x; int wv = tid >> 6; int l = tid & 63;
    int lm = l & 15, lk = l >> 4;

    half8 af[16];
    int trow = tb + wv * 16 + lm;
    const unsigned long long* abase = h1buf + ((size_t)(trow + 1) * 8 + b) * 128;
    #pragma unroll
    for (int kt = 0; kt < 16; kt++)
        af[kt] = mkfrag(abase[kt * 8 + lk * 2], abase[kt * 8 + lk * 2 + 1]);

    f32x4 acc[16];
    #pragma unroll
    for (int nt = 0; nt < 16; nt++) {
        f32x4 z = {0.f, 0.f, 0.f, 0.f}; acc[nt] = z;
        #pragma unroll
        for (int kt = 0; kt < 16; kt++) {
            int n = nt * 16 + lm; int k = kt * 32 + lk * 8;
            half8 bw = *(const half8*)&prew16[(size_t)n * HD + k];
            acc[nt] = mfma(af[kt], bw, acc[nt]);
        }
    }
    __shared__ __align__(16) unsigned short pt[64][264];
    #pragma unroll
    for (int nt = 0; nt < 16; nt++) {
        float pb = pre_b[nt * 16 + lm];
        #pragma unroll
        for (int r2 = 0; r2 < 4; r2++)
            pt[wv * 16 + lk * 4 + r2][nt * 16 + lm] = f2h_bits(tanhf_(acc[nt][r2] + pb));
    }
    __syncthreads();
    f32x4 a2[2];
    { f32x4 z = {0.f, 0.f, 0.f, 0.f}; a2[0] = z; a2[1] = z; }
    #pragma unroll
    for (int kt = 0; kt < 8; kt++) {
        half8 pa = *(const half8*)&pt[wv * 16 + lm][kt * 32 + lk * 8];
        #pragma unroll
        for (int nt = 0; nt < 2; nt++) {
            int n = nt * 16 + lm;
            half8 bw = (n < NSS) ? *(const half8*)&outw16[(size_t)n * NPRE + kt * 32 + lk * 8]
                                 : mkfrag(0ull, 0ull);
            a2[nt] = mfma(pa, bw, a2[nt]);
        }
    }
    #pragma unroll
    for (int nt = 0; nt < 2; nt++) {
        int n = nt * 16 + lm;
        if (n < NSS) {
            float ob = out_b[n];
            #pragma unroll
            for (int r2 = 0; r2 < 4; r2++) {
                int t = tb + wv * 16 + lk * 4 + r2;
                out[((size_t)b * TT + t) * NSS + n] = a2[nt][r2] + ob;
            }
        }
    }
}

// ---------------- launch ----------------
extern "C" void kernel_launch(void* const* d_in, const int* in_sizes, int n_in,
                              void* d_out, int out_size, void* d_ws, size_t ws_size,
                              hipStream_t stream) {
    const float* mel  = (const float*)d_in[0];
    const float* xlow = (const float*)d_in[1];
    const float* gsx  = (const float*)d_in[2];
    const float* cw0  = (const float*)d_in[3];
    const float* cb0  = (const float*)d_in[4];
    const float* cw1  = (const float*)d_in[5];
    const float* cb1  = (const float*)d_in[6];
    const float* cw2  = (const float*)d_in[7];
    const float* cb2  = (const float*)d_in[8];
    const float* wih0 = (const float*)d_in[9];
    const float* whh0 = (const float*)d_in[10];
    const float* bih0 = (const float*)d_in[11];
    const float* bhh0 = (const float*)d_in[12];
    const float* wih1 = (const float*)d_in[13];
    const float* whh1 = (const float*)d_in[14];
    const float* bih1 = (const float*)d_in[15];
    const float* bhh1 = (const float*)d_in[16];
    const float* prew = (const float*)d_in[17];
    const float* preb = (const float*)d_in[18];
    const float* outw = (const float*)d_in[19];
    const float* outb = (const float*)d_in[20];

    size_t needed = 2 * HB_BYTES + CONV_BYTES + INTERP_BYTES + PREW16_BYTES + OUTW16_BYTES;
    if (ws_size < needed) return;

    char* ws = (char*)d_ws;
    unsigned long long* h0buf = (unsigned long long*)ws;
    unsigned long long* h1buf = (unsigned long long*)(ws + HB_BYTES);
    float* convout = (float*)(ws + 2 * HB_BYTES);
    float* interp  = (float*)(ws + 2 * HB_BYTES + CONV_BYTES);
    unsigned short* prew16 = (unsigned short*)(ws + 2 * HB_BYTES + CONV_BYTES + INTERP_BYTES);
    unsigned short* outw16 = (unsigned short*)(ws + 2 * HB_BYTES + CONV_BYTES + INTERP_BYTES + PREW16_BYTES);

    // sentinel-init both h broadcast buffers (0xFF.. = NaN fp16 pairs / 0xFFFFFFFF u32 sentinel)
    hipMemsetAsync(ws, 0xFF, 2 * HB_BYTES, stream);

    k_prep<<<(NPRE * HD + 255) / 256, 256, 0, stream>>>(prew, outw, prew16, outw16);
    k_conv<<<32, 256, 0, stream>>>(xlow, cw0, cb0, cw1, cb1, cw2, cb2, convout, interp);
    k_rnn<<<64, 64, 0, stream>>>(mel, gsx, convout, interp,
                                 wih0, whh0, bih0, bhh0,
                                 wih1, whh1, bih1, bhh1,
                                 h0buf, h1buf);
    k_final<<<1000, 256, 0, stream>>>(h1buf, prew16, preb, outw16, outb, (float*)d_out);
}

// Round 12
// 44771.365 us; speedup vs baseline: 1.0317x; 1.0317x over previous
//
#include <hip/hip_runtime.h>
#include <hip/hip_fp16.h>
#include <stdint.h>

// ---------------- problem constants ----------------
#define TT     8000
#define TLOW   800
#define TMEL   80
#define NMEL   80
#define NB     8
#define HD     512
#define LC     20
#define NPRE   256
#define NSS    30

// h broadcast buffers: slot s holds h[s-1]; slot 0 = zeros. per slot: 8 batches x 128 u64 (512 fp16)
#define HB_SLOTS (TT + 1)
#define HB_U64   ((size_t)HB_SLOTS * 8 * 128)
#define HB_BYTES (HB_U64 * 8)
#define CONV_BYTES   ((size_t)NB * TLOW * LC * 4)
#define INTERP_BYTES ((size_t)NB * TT * 4)
#define PREW16_BYTES ((size_t)NPRE * HD * 2)
#define OUTW16_BYTES ((size_t)NSS * NPRE * 2)

typedef __attribute__((ext_vector_type(8))) _Float16 half8;
typedef __attribute__((ext_vector_type(4))) float f32x4;

static __device__ __forceinline__ unsigned short f2h_bits(float f) {
    union { _Float16 h; unsigned short u; } c; c.h = (_Float16)f; return c.u;  // RNE
}
static __device__ __forceinline__ float sigf(float x) {
    x = fminf(30.f, fmaxf(-30.f, x));
    return 1.f / (1.f + __expf(-x));
}
static __device__ __forceinline__ float tanhf_(float x) {
    x = fminf(15.f, fmaxf(-15.f, x));
    float e = __expf(2.f * x);
    return (e - 1.f) / (e + 1.f);
}
static __device__ __forceinline__ half8 mkfrag(unsigned long long a, unsigned long long b) {
    union { unsigned long long q[2]; half8 v; } u; u.q[0] = a; u.q[1] = b; return u.v;
}
static __device__ __forceinline__ f32x4 mfma(half8 a, half8 b, f32x4 c) {
    return __builtin_amdgcn_mfma_f32_16x16x32_f16(a, b, c, 0, 0, 0);
}

// ---------------- poll primitives ----------------
// Agent-scope data-carrying batch (guaranteed-progress path: LLC-visible).
static __device__ __forceinline__ void issue16(const unsigned long long* __restrict__ p,
                                               int lane, unsigned long long* __restrict__ q)
{
    #pragma unroll
    for (int k = 0; k < 16; k++)
        q[k] = __hip_atomic_load(p + lane + 64 * k, __ATOMIC_RELAXED, __HIP_MEMORY_SCOPE_AGENT);
}
// XCD-L2 fast path: sc0 loads bypass L1 but are served by the (XCD-shared) L2.
// If producer+consumer share an XCD, the agent-scope publish write-through makes
// this visible at L2 latency. Correctness never depends on it (agent fallback).
static __device__ __forceinline__ void issue16_l2(const unsigned long long* __restrict__ p,
                                                  int lane, unsigned long long* __restrict__ q)
{
    const unsigned long long* a0 = p + lane;        // k = 0..7  (offset 0..3584 B)
    const unsigned long long* a1 = a0 + 512;        // +4096 B, k = 8..15
    asm volatile(
        "global_load_dwordx2 %0, %16, off sc0\n\t"
        "global_load_dwordx2 %1, %16, off offset:512 sc0\n\t"
        "global_load_dwordx2 %2, %16, off offset:1024 sc0\n\t"
        "global_load_dwordx2 %3, %16, off offset:1536 sc0\n\t"
        "global_load_dwordx2 %4, %16, off offset:2048 sc0\n\t"
        "global_load_dwordx2 %5, %16, off offset:2560 sc0\n\t"
        "global_load_dwordx2 %6, %16, off offset:3072 sc0\n\t"
        "global_load_dwordx2 %7, %16, off offset:3584 sc0\n\t"
        "global_load_dwordx2 %8, %17, off sc0\n\t"
        "global_load_dwordx2 %9, %17, off offset:512 sc0\n\t"
        "global_load_dwordx2 %10, %17, off offset:1024 sc0\n\t"
        "global_load_dwordx2 %11, %17, off offset:1536 sc0\n\t"
        "global_load_dwordx2 %12, %17, off offset:2048 sc0\n\t"
        "global_load_dwordx2 %13, %17, off offset:2560 sc0\n\t"
        "global_load_dwordx2 %14, %17, off offset:3072 sc0\n\t"
        "global_load_dwordx2 %15, %17, off offset:3584 sc0\n\t"
        "s_waitcnt vmcnt(0)"
        : "=&v"(q[0]), "=&v"(q[1]), "=&v"(q[2]), "=&v"(q[3]),
          "=&v"(q[4]), "=&v"(q[5]), "=&v"(q[6]), "=&v"(q[7]),
          "=&v"(q[8]), "=&v"(q[9]), "=&v"(q[10]), "=&v"(q[11]),
          "=&v"(q[12]), "=&v"(q[13]), "=&v"(q[14]), "=&v"(q[15])
        : "v"(a0), "v"(a1)
        : "memory");
}
static __device__ __forceinline__ bool good16(const unsigned long long* __restrict__ q)
{
    bool bad = false;
    #pragma unroll
    for (int k = 0; k < 16; k++) {
        unsigned int lo = (unsigned int)q[k], hi = (unsigned int)(q[k] >> 32);
        bad |= (lo == 0xFFFFFFFFu) | (hi == 0xFFFFFFFFu);
    }
    return !__any(bad);
}
static __device__ __forceinline__ void stage16(unsigned long long* __restrict__ st,
                                               int lane, const unsigned long long* __restrict__ q)
{
    #pragma unroll
    for (int k = 0; k < 16; k++) { int i = lane + 64 * k; st[(i >> 7) * 129 + (i & 127)] = q[k]; }
}
// Critical-edge poll: L2 fast samples, agent-scope every 4th (guaranteed progress).
static __device__ void poll_fast(const unsigned long long* __restrict__ slot,
                                 int lane, unsigned long long* __restrict__ st)
{
    unsigned long long q[16];
    for (int it = 0; ; ++it) {
        if ((it & 3) == 3) issue16(slot, lane, q);
        else               issue16_l2(slot, lane, q);
        if (good16(q)) break;
        if ((it & 3) == 3) __builtin_amdgcn_s_sleep(1);
    }
    stage16(st, lane, q);
}
// Off-critical-path poll (source usually ready): agent-scope + sleep backoff.
static __device__ void poll_sleep(const unsigned long long* __restrict__ slot,
                                  int lane, unsigned long long* __restrict__ st)
{
    unsigned long long q[16];
    for (;;) {
        issue16(slot, lane, q);
        if (good16(q)) break;
        __builtin_amdgcn_s_sleep(1);
    }
    stage16(st, lane, q);
}
// frag read from staged slot: batch = lane&7 (cols 8-15 mirror, discarded on write)
static __device__ __forceinline__ half8 ldsfrag(const unsigned long long* __restrict__ st,
                                                int lane, int kt)
{
    int base = (lane & 7) * 129 + ((lane >> 4) << 1) + kt * 8;
    return mkfrag(st[base], st[base + 1]);
}

// ---------------- K0: convert pre_w / out_w to fp16 ----------------
__global__ __launch_bounds__(256) void k_prep(
    const float* __restrict__ pre_w, const float* __restrict__ out_w,
    unsigned short* __restrict__ prew16, unsigned short* __restrict__ outw16)
{
    int i = blockIdx.x * 256 + threadIdx.x;
    if (i < NPRE * HD) prew16[i] = f2h_bits(pre_w[i]);
    if (i < NSS * NPRE) outw16[i] = f2h_bits(out_w[i]);
}

// ---------------- K1: conv stack + linear interp (all f32) ----------------
#define CHW 218   // 200 + 2*9 halo (3 conv layers x pad 3)
__global__ __launch_bounds__(256) void k_conv(
    const float* __restrict__ xlow,
    const float* __restrict__ w0, const float* __restrict__ cb0,
    const float* __restrict__ w1, const float* __restrict__ cb1,
    const float* __restrict__ w2, const float* __restrict__ cb2,
    float* __restrict__ convout, float* __restrict__ interp)
{
    int blk = blockIdx.x; int b = blk >> 2; int ch = blk & 3; int cb = ch * 200;
    int tid = threadIdx.x;
    __shared__ float xr[224];
    __shared__ float w0l[LC * 7], w1l[LC * LC * 7], w2l[LC * LC * 7];
    __shared__ float b0l[LC], b1l[LC], b2l[LC];
    __shared__ float h0[LC][CHW], h1[LC][CHW];

    for (int i = tid; i < LC * 7; i += 256) w0l[i] = w0[i];
    for (int i = tid; i < LC * LC * 7; i += 256) { w1l[i] = w1[i]; w2l[i] = w2[i]; }
    for (int i = tid; i < LC; i += 256) { b0l[i] = cb0[i]; b1l[i] = cb1[i]; b2l[i] = cb2[i]; }
    for (int i = tid; i < 224; i += 256) {
        int g = cb - 12 + i;
        xr[i] = (g >= 0 && g < TLOW) ? xlow[b * TLOW + g] : 0.f;
    }
    __syncthreads();
    for (int i = tid; i < LC * CHW; i += 256) {
        int c = i / CHW, s = i - c * CHW;
        int tg = cb - 9 + s;
        float a = b0l[c];
        #pragma unroll
        for (int j = 0; j < 7; j++) a += w0l[c * 7 + j] * xr[s + j];
        h0[c][s] = (tg >= 0 && tg < TLOW) ? tanhf_(a) : 0.f;
    }
    __syncthreads();
    for (int i = tid; i < LC * CHW; i += 256) {
        int c = i / CHW, s = i - c * CHW;
        int tg = cb - 9 + s;
        float a = b1l[c];
        for (int ci = 0; ci < LC; ci++) {
            #pragma unroll
            for (int j = 0; j < 7; j++) {
                int ss = s + j - 3;
                float hv = (ss >= 0 && ss < CHW) ? h0[ci][ss] : 0.f;
                a += w1l[(c * LC + ci) * 7 + j] * hv;
            }
        }
        h1[c][s] = (tg >= 0 && tg < TLOW) ? tanhf_(a) : 0.f;
    }
    __syncthreads();
    for (int i = tid; i < LC * 200; i += 256) {
        int c = i / 200, t0 = i - c * 200; int s = t0 + 9;
        float a = b2l[c];
        for (int ci = 0; ci < LC; ci++) {
            #pragma unroll
            for (int j = 0; j < 7; j++) a += w2l[(c * LC + ci) * 7 + j] * h1[ci][s + j - 3];
        }
        convout[((size_t)b * TLOW + cb + t0) * LC + c] = tanhf_(a);
    }
    for (int i = tid; i < 2000; i += 256) {
        int t = cb * 10 + i;
        float src = ((float)t + 0.5f) * 0.1f - 0.5f;
        src = fminf(fmaxf(src, 0.f), (float)(TLOW - 1));
        int i0 = (int)floorf(src); int i1 = (i0 + 1 < TLOW) ? i0 + 1 : TLOW - 1;
        float w = src - (float)i0;
        interp[(size_t)b * TT + t] = xlow[b * TLOW + i0] * (1.f - w) + xlow[b * TLOW + i1] * w;
    }
}

// ---------------- K2: persistent GRU recurrence ----------------
// grid: 512 blocks x 192 threads; only blockIdx%8==0 survive (64 real blocks ->
// one XCD under round-robin placement; 2 blocks/CU on 32 CUs, co-residency
// guaranteed by __launch_bounds__(192,2) VGPR cap). Real blk: 0-31 = layer0
// chunks (16 h each), 32-63 = layer1. Roles: wv=gate worker; wv0 also cell+
// publish; wv1 also edge poller (L2 fast path); wv2 (L1) h0-prefetch poller.
// 2 barriers/step; publish runs CONCURRENT with next-slot poll.
__global__ __launch_bounds__(192, 2) void k_rnn(
    const float* __restrict__ mel, const float* __restrict__ gsx,
    const float* __restrict__ convout, const float* __restrict__ interp,
    const float* __restrict__ wih0, const float* __restrict__ whh0,
    const float* __restrict__ bih0, const float* __restrict__ bhh0,
    const float* __restrict__ wih1, const float* __restrict__ whh1,
    const float* __restrict__ bih1, const float* __restrict__ bhh1,
    unsigned long long* __restrict__ h0buf, unsigned long long* __restrict__ h1buf)
{
    if (blockIdx.x & 7) return;               // XCD pinning: keep ≡0 (mod 8)
    const int blk = blockIdx.x >> 3;          // 0..63
    const int tid = threadIdx.x;
    const int wv = tid >> 6;                  // 0..2 : gate (r,z,n)
    const int lane = tid & 63;
    const int lm = lane & 15, lk = lane >> 4;
    const bool isL0 = (blk < 32);
    const int cbid = isL0 ? blk : (blk - 32);
    const int cb = cbid * 16;                 // h-index chunk base
    const int row = wv * 512 + cb + lm;       // gate weight row for this lane

    __shared__ float exch[3][2][16][9];        // [gate][x/h][row][batch(pad 9)]
    __shared__ __align__(16) unsigned short xv[2][16][136];  // L0 input, double-buffered
    __shared__ unsigned long long stX[8 * 129]; // staged h0 slot (L1 x-part)
    __shared__ unsigned long long stH[8 * 129]; // staged edge slot (L0: h0; L1: h1)

    // cell lanes (wv0, 64 lanes): batch bb = lane>>3, rows i0=2*(lane&7), i1=i0+1
    const int cbb = lane >> 3;
    const int ci0 = (lane & 7) * 2, ci1 = ci0 + 1;
    float hr0 = 0.f, hr1 = 0.f;                // f32 recurrence state (registers)
    float bi0[3], bi1[3], bh0[3], bh1[3];
    if (wv == 0) {
        const float* bi = isL0 ? bih0 : bih1;
        const float* bh = isL0 ? bhh0 : bhh1;
        #pragma unroll
        for (int g = 0; g < 3; g++) {
            bi0[g] = bi[g * 512 + cb + ci0]; bi1[g] = bi[g * 512 + cb + ci1];
            bh0[g] = bh[g * 512 + cb + ci0]; bh1[g] = bh[g * 512 + cb + ci1];
        }
    }
    for (int i = tid; i < 2 * 16 * 136; i += 192) (&xv[0][0][0])[i] = 0;

    // publish h[-1] = 0 for own chunk (slot 0): 64 u32 stores by wv0
    if (wv == 0) {
        unsigned long long* buf = isL0 ? h0buf : h1buf;
        unsigned int* o32 = (unsigned int*)buf + (size_t)cbb * 256 + (cb >> 1) + (lane & 7);
        __hip_atomic_store(o32, 0u, __ATOMIC_RELAXED, __HIP_MEMORY_SCOPE_AGENT);
    }

    if (isL0) {
        // weights in regs: wfx = wih0 (K 0..127, cols >=102 zero), wfh = whh0
        half8 wfx[4], wfh[16];
        #pragma unroll
        for (int kt = 0; kt < 4; kt++)
            #pragma unroll
            for (int j = 0; j < 8; j++) {
                int k = kt * 32 + lk * 8 + j;
                wfx[kt][j] = (k < 102) ? (_Float16)wih0[(size_t)row * 102 + k] : (_Float16)0.f;
            }
        #pragma unroll
        for (int kt = 0; kt < 16; kt++)
            #pragma unroll
            for (int j = 0; j < 8; j++)
                wfh[kt][j] = (_Float16)whh0[(size_t)row * 512 + kt * 32 + lk * 8 + j];

        // initial xv[0] = x(0)
        {
            float pf[5];
            #pragma unroll
            for (int u = 0; u < 5; u++) {
                int e = tid + 192 * u; float v = 0.f;
                if (e < 816) {
                    int bb = e / 102, k = e - 102 * bb;
                    if (k < 80)       v = mel[((size_t)bb * TMEL + 0) * NMEL + k];
                    else if (k < 100) v = convout[((size_t)bb * TLOW + 0) * LC + (k - 80)];
                    else if (k == 100) v = interp[(size_t)bb * TT + 0];
                    else               v = gsx[(size_t)bb * TT + 0];
                }
                pf[u] = v;
            }
            #pragma unroll
            for (int u = 0; u < 5; u++) {
                int e = tid + 192 * u;
                if (e < 816) { int bb = e / 102, k = e - 102 * bb; xv[0][bb][k] = f2h_bits(pf[u]); }
            }
        }
        // prologue: stage slot 0 (h[-1] = zeros)
        if (wv == 1) poll_sleep(h0buf, lane, stH);
        __syncthreads();

        for (int t = 0; t < TT; t++) {
            // prefetch x(t+1): issue early, consume after MFMA
            int tn = (t + 1 < TT) ? (t + 1) : (TT - 1);
            int tmi = tn / 100, tli = tn / 10;
            float pf[5];
            #pragma unroll
            for (int u = 0; u < 5; u++) {
                int e = tid + 192 * u; float v = 0.f;
                if (e < 816) {
                    int bb = e / 102, k = e - 102 * bb;
                    if (k < 80)       v = mel[((size_t)bb * TMEL + tmi) * NMEL + k];
                    else if (k < 100) v = convout[((size_t)bb * TLOW + tli) * LC + (k - 80)];
                    else if (k == 100) v = interp[(size_t)bb * TT + tn];
                    else               v = gsx[(size_t)bb * TT + tn];
                }
                pf[u] = v;
            }

            f32x4 accX = {0.f, 0.f, 0.f, 0.f};
            #pragma unroll
            for (int kt = 0; kt < 4; kt++) {
                half8 xf = *(const half8*)&xv[t & 1][lm][kt * 32 + lk * 8];
                accX = mfma(wfx[kt], xf, accX);
            }
            f32x4 a0 = {0.f, 0.f, 0.f, 0.f}, a1 = {0.f, 0.f, 0.f, 0.f};
            #pragma unroll
            for (int i = 0; i < 8; i++) a0 = mfma(wfh[i], ldsfrag(stH, lane, i), a0);
            #pragma unroll
            for (int i = 0; i < 8; i++) a1 = mfma(wfh[8 + i], ldsfrag(stH, lane, 8 + i), a1);
            f32x4 accH = a0 + a1;

            if (lm < 8) {
                #pragma unroll
                for (int r2 = 0; r2 < 4; r2++) {
                    exch[wv][0][lk * 4 + r2][lm] = accX[r2];
                    exch[wv][1][lk * 4 + r2][lm] = accH[r2];
                }
            }
            #pragma unroll
            for (int u = 0; u < 5; u++) {
                int e = tid + 192 * u;
                if (e < 816) { int bb = e / 102, k = e - 102 * bb; xv[(t + 1) & 1][bb][k] = f2h_bits(pf[u]); }
            }
            __syncthreads();   // B2: exch ready, stH consumed
            if (wv == 0) {
                float Xr0 = exch[0][0][ci0][cbb], Hr0 = exch[0][1][ci0][cbb];
                float Xz0 = exch[1][0][ci0][cbb], Hz0 = exch[1][1][ci0][cbb];
                float Xn0 = exch[2][0][ci0][cbb], Hn0 = exch[2][1][ci0][cbb];
                float r0 = sigf(Xr0 + Hr0 + bi0[0] + bh0[0]);
                float z0 = sigf(Xz0 + Hz0 + bi0[1] + bh0[1]);
                float n0 = tanhf_(Xn0 + bi0[2] + r0 * (Hn0 + bh0[2]));
                hr0 = (1.f - z0) * n0 + z0 * hr0;
                float Xr1 = exch[0][0][ci1][cbb], Hr1 = exch[0][1][ci1][cbb];
                float Xz1 = exch[1][0][ci1][cbb], Hz1 = exch[1][1][ci1][cbb];
                float Xn1 = exch[2][0][ci1][cbb], Hn1 = exch[2][1][ci1][cbb];
                float r1 = sigf(Xr1 + Hr1 + bi1[0] + bh1[0]);
                float z1 = sigf(Xz1 + Hz1 + bi1[1] + bh1[1]);
                float n1 = tanhf_(Xn1 + bi1[2] + r1 * (Hn1 + bh1[2]));
                hr1 = (1.f - z1) * n1 + z1 * hr1;
                unsigned int pk = (unsigned int)f2h_bits(hr0) | ((unsigned int)f2h_bits(hr1) << 16);
                unsigned int* o32 = (unsigned int*)(h0buf + (size_t)(t + 1) * 1024)
                                  + (size_t)cbb * 256 + (cb >> 1) + (lane & 7);
                __hip_atomic_store(o32, pk, __ATOMIC_RELAXED, __HIP_MEMORY_SCOPE_AGENT);
            } else if (wv == 1) {
                poll_fast(h0buf + (size_t)(t + 1) * 1024, lane, stH);  // spins while wv0 publishes
            }
            __syncthreads();   // B1: stH(t+1) staged
        }
    } else {
        // layer 1: wfx = wih1 (consumes h0), wfh = whh1 (consumes h1)
        half8 wfx[16], wfh[16];
        #pragma unroll
        for (int kt = 0; kt < 16; kt++)
            #pragma unroll
            for (int j = 0; j < 8; j++) {
                wfx[kt][j] = (_Float16)wih1[(size_t)row * 512 + kt * 32 + lk * 8 + j];
                wfh[kt][j] = (_Float16)whh1[(size_t)row * 512 + kt * 32 + lk * 8 + j];
            }
        // prologue: stage h1 slot 0 (zeros) and h0 slot 1 (= h0[0])
        if (wv == 1)      poll_sleep(h1buf, lane, stH);
        else if (wv == 2) poll_sleep(h0buf + 1024, lane, stX);
        __syncthreads();

        for (int t = 0; t < TT; t++) {
            f32x4 x0 = {0.f, 0.f, 0.f, 0.f}, x1 = {0.f, 0.f, 0.f, 0.f};
            #pragma unroll
            for (int i = 0; i < 8; i++) x0 = mfma(wfx[i],     ldsfrag(stX, lane, i),     x0);
            #pragma unroll
            for (int i = 0; i < 8; i++) x1 = mfma(wfx[8 + i], ldsfrag(stX, lane, 8 + i), x1);
            f32x4 accX = x0 + x1;
            f32x4 a0 = {0.f, 0.f, 0.f, 0.f}, a1 = {0.f, 0.f, 0.f, 0.f};
            #pragma unroll
            for (int i = 0; i < 8; i++) a0 = mfma(wfh[i],     ldsfrag(stH, lane, i),     a0);
            #pragma unroll
            for (int i = 0; i < 8; i++) a1 = mfma(wfh[8 + i], ldsfrag(stH, lane, 8 + i), a1);
            f32x4 accH = a0 + a1;

            if (lm < 8) {
                #pragma unroll
                for (int r2 = 0; r2 < 4; r2++) {
                    exch[wv][0][lk * 4 + r2][lm] = accX[r2];
                    exch[wv][1][lk * 4 + r2][lm] = accH[r2];
                }
            }
            __syncthreads();   // B2: exch ready, stX/stH consumed
            if (wv == 0) {
                float Xr0 = exch[0][0][ci0][cbb], Hr0 = exch[0][1][ci0][cbb];
                float Xz0 = exch[1][0][ci0][cbb], Hz0 = exch[1][1][ci0][cbb];
                float Xn0 = exch[2][0][ci0][cbb], Hn0 = exch[2][1][ci0][cbb];
                float r0 = sigf(Xr0 + Hr0 + bi0[0] + bh0[0]);
                float z0 = sigf(Xz0 + Hz0 + bi0[1] + bh0[1]);
                float n0 = tanhf_(Xn0 + bi0[2] + r0 * (Hn0 + bh0[2]));
                hr0 = (1.f - z0) * n0 + z0 * hr0;
                float Xr1 = exch[0][0][ci1][cbb], Hr1 = exch[0][1][ci1][cbb];
                float Xz1 = exch[1][0][ci1][cbb], Hz1 = exch[1][1][ci1][cbb];
                float Xn1 = exch[2][0][ci1][cbb], Hn1 = exch[2][1][ci1][cbb];
                float r1 = sigf(Xr1 + Hr1 + bi1[0] + bh1[0]);
                float z1 = sigf(Xz1 + Hz1 + bi1[1] + bh1[1]);
                float n1 = tanhf_(Xn1 + bi1[2] + r1 * (Hn1 + bh1[2]));
                hr1 = (1.f - z1) * n1 + z1 * hr1;
                unsigned int pk = (unsigned int)f2h_bits(hr0) | ((unsigned int)f2h_bits(hr1) << 16);
                unsigned int* o32 = (unsigned int*)(h1buf + (size_t)(t + 1) * 1024)
                                  + (size_t)cbb * 256 + (cb >> 1) + (lane & 7);
                __hip_atomic_store(o32, pk, __ATOMIC_RELAXED, __HIP_MEMORY_SCOPE_AGENT);
            } else if (wv == 1) {
                poll_fast(h1buf + (size_t)(t + 1) * 1024, lane, stH);  // edge; overlaps publish
            } else if (wv == 2) {
                if (t + 2 <= TT) poll_sleep(h0buf + (size_t)(t + 2) * 1024, lane, stX);
            }
            __syncthreads();   // B1
        }
    }
}

// ---------------- K3: fused head ----------------
__global__ __launch_bounds__(256) void k_final(
    const unsigned long long* __restrict__ h1buf,
    const unsigned short* __restrict__ prew16, const float* __restrict__ pre_b,
    const unsigned short* __restrict__ outw16, const float* __restrict__ out_b,
    float* __restrict__ out)
{
    int blk = blockIdx.x; int b = blk / 125; int tb = (blk - b * 125) * 64;
    int tid = threadIdx.x; int wv = tid >> 6; int l = tid & 63;
    int lm = l & 15, lk = l >> 4;

    half8 af[16];
    int trow = tb + wv * 16 + lm;
    const unsigned long long* abase = h1buf + ((size_t)(trow + 1) * 8 + b) * 128;
    #pragma unroll
    for (int kt = 0; kt < 16; kt++)
        af[kt] = mkfrag(abase[kt * 8 + lk * 2], abase[kt * 8 + lk * 2 + 1]);

    f32x4 acc[16];
    #pragma unroll
    for (int nt = 0; nt < 16; nt++) {
        f32x4 z = {0.f, 0.f, 0.f, 0.f}; acc[nt] = z;
        #pragma unroll
        for (int kt = 0; kt < 16; kt++) {
            int n = nt * 16 + lm; int k = kt * 32 + lk * 8;
            half8 bw = *(const half8*)&prew16[(size_t)n * HD + k];
            acc[nt] = mfma(af[kt], bw, acc[nt]);
        }
    }
    __shared__ __align__(16) unsigned short pt[64][264];
    #pragma unroll
    for (int nt = 0; nt < 16; nt++) {
        float pb = pre_b[nt * 16 + lm];
        #pragma unroll
        for (int r2 = 0; r2 < 4; r2++)
            pt[wv * 16 + lk * 4 + r2][nt * 16 + lm] = f2h_bits(tanhf_(acc[nt][r2] + pb));
    }
    __syncthreads();
    f32x4 a2[2];
    { f32x4 z = {0.f, 0.f, 0.f, 0.f}; a2[0] = z; a2[1] = z; }
    #pragma unroll
    for (int kt = 0; kt < 8; kt++) {
        half8 pa = *(const half8*)&pt[wv * 16 + lm][kt * 32 + lk * 8];
        #pragma unroll
        for (int nt = 0; nt < 2; nt++) {
            int n = nt * 16 + lm;
            half8 bw = (n < NSS) ? *(const half8*)&outw16[(size_t)n * NPRE + kt * 32 + lk * 8]
                                 : mkfrag(0ull, 0ull);
            a2[nt] = mfma(pa, bw, a2[nt]);
        }
    }
    #pragma unroll
    for (int nt = 0; nt < 2; nt++) {
        int n = nt * 16 + lm;
        if (n < NSS) {
            float ob = out_b[n];
            #pragma unroll
            for (int r2 = 0; r2 < 4; r2++) {
                int t = tb + wv * 16 + lk * 4 + r2;
                out[((size_t)b * TT + t) * NSS + n] = a2[nt][r2] + ob;
            }
        }
    }
}

// ---------------- launch ----------------
extern "C" void kernel_launch(void* const* d_in, const int* in_sizes, int n_in,
                              void* d_out, int out_size, void* d_ws, size_t ws_size,
                              hipStream_t stream) {
    const float* mel  = (const float*)d_in[0];
    const float* xlow = (const float*)d_in[1];
    const float* gsx  = (const float*)d_in[2];
    const float* cw0  = (const float*)d_in[3];
    const float* cb0  = (const float*)d_in[4];
    const float* cw1  = (const float*)d_in[5];
    const float* cb1  = (const float*)d_in[6];
    const float* cw2  = (const float*)d_in[7];
    const float* cb2  = (const float*)d_in[8];
    const float* wih0 = (const float*)d_in[9];
    const float* whh0 = (const float*)d_in[10];
    const float* bih0 = (const float*)d_in[11];
    const float* bhh0 = (const float*)d_in[12];
    const float* wih1 = (const float*)d_in[13];
    const float* whh1 = (const float*)d_in[14];
    const float* bih1 = (const float*)d_in[15];
    const float* bhh1 = (const float*)d_in[16];
    const float* prew = (const float*)d_in[17];
    const float* preb = (const float*)d_in[18];
    const float* outw = (const float*)d_in[19];
    const float* outb = (const float*)d_in[20];

    size_t needed = 2 * HB_BYTES + CONV_BYTES + INTERP_BYTES + PREW16_BYTES + OUTW16_BYTES;
    if (ws_size < needed) return;

    char* ws = (char*)d_ws;
    unsigned long long* h0buf = (unsigned long long*)ws;
    unsigned long long* h1buf = (unsigned long long*)(ws + HB_BYTES);
    float* convout = (float*)(ws + 2 * HB_BYTES);
    float* interp  = (float*)(ws + 2 * HB_BYTES + CONV_BYTES);
    unsigned short* prew16 = (unsigned short*)(ws + 2 * HB_BYTES + CONV_BYTES + INTERP_BYTES);
    unsigned short* outw16 = (unsigned short*)(ws + 2 * HB_BYTES + CONV_BYTES + INTERP_BYTES + PREW16_BYTES);

    // sentinel-init both h broadcast buffers (0xFF.. = NaN fp16 pairs / 0xFFFFFFFF u32 sentinel)
    hipMemsetAsync(ws, 0xFF, 2 * HB_BYTES, stream);

    k_prep<<<(NPRE * HD + 255) / 256, 256, 0, stream>>>(prew, outw, prew16, outw16);
    k_conv<<<32, 256, 0, stream>>>(xlow, cw0, cb0, cw1, cb1, cw2, cb2, convout, interp);
    k_rnn<<<512, 192, 0, stream>>>(mel, gsx, convout, interp,
                                   wih0, whh0, bih0, bhh0,
                                   wih1, whh1, bih1, bhh1,
                                   h0buf, h1buf);
    k_final<<<1000, 256, 0, stream>>>(h1buf, prew16, preb, outw16, outb, (float*)d_out);
}

// Round 13
// 20269.901 us; speedup vs baseline: 2.2788x; 2.2088x over previous
//
#include <hip/hip_runtime.h>
#include <hip/hip_fp16.h>
#include <stdint.h>

// ---------------- problem constants ----------------
#define TT     8000
#define TLOW   800
#define TMEL   80
#define NMEL   80
#define NB     8
#define HD     512
#define LC     20
#define NPRE   256
#define NSS    30

// h broadcast buffers: slot s holds h[s-1]; slot 0 = zeros. per slot: 8 batches x 128 u64 (512 fp16)
#define HB_SLOTS (TT + 1)
#define HB_U64   ((size_t)HB_SLOTS * 8 * 128)
#define HB_BYTES (HB_U64 * 8)
#define CONV_BYTES   ((size_t)NB * TLOW * LC * 4)
#define INTERP_BYTES ((size_t)NB * TT * 4)
#define PREW16_BYTES ((size_t)NPRE * HD * 2)
#define OUTW16_BYTES ((size_t)NSS * NPRE * 2)

typedef __attribute__((ext_vector_type(8))) _Float16 half8;
typedef __attribute__((ext_vector_type(4))) float f32x4;

static __device__ __forceinline__ unsigned short f2h_bits(float f) {
    union { _Float16 h; unsigned short u; } c; c.h = (_Float16)f; return c.u;  // RNE
}
static __device__ __forceinline__ float sigf(float x) {
    x = fminf(30.f, fmaxf(-30.f, x));
    return 1.f / (1.f + __expf(-x));
}
static __device__ __forceinline__ float tanhf_(float x) {
    x = fminf(15.f, fmaxf(-15.f, x));
    float e = __expf(2.f * x);
    return (e - 1.f) / (e + 1.f);
}
static __device__ __forceinline__ half8 mkfrag(unsigned long long a, unsigned long long b) {
    union { unsigned long long q[2]; half8 v; } u; u.q[0] = a; u.q[1] = b; return u.v;
}
static __device__ __forceinline__ f32x4 mfma(half8 a, half8 b, f32x4 c) {
    return __builtin_amdgcn_mfma_f32_16x16x32_f16(a, b, c, 0, 0, 0);
}

// ---------------- single-wave slot poll + LDS stage ----------------
// One wave polls a whole 1024-u64 slot (lane l owns words l+64k), sentinel =
// 0xFFFFFFFF per u32 half (fp16 NaN pair). Data-carrying: the batch that
// detects readiness IS the data. On success, stages to LDS [8][129].
static __device__ __forceinline__ void poll_stage(const unsigned long long* __restrict__ slot,
                                                  int lane, unsigned long long* __restrict__ st)
{
    unsigned long long v[16];
    for (;;) {
        #pragma unroll
        for (int k = 0; k < 16; k++)
            v[k] = __hip_atomic_load(slot + lane + 64 * k, __ATOMIC_RELAXED, __HIP_MEMORY_SCOPE_AGENT);
        bool bad = false;
        #pragma unroll
        for (int k = 0; k < 16; k++) {
            unsigned int lo = (unsigned int)v[k], hi = (unsigned int)(v[k] >> 32);
            bad |= (lo == 0xFFFFFFFFu) | (hi == 0xFFFFFFFFu);
        }
        if (!__any(bad)) break;
        __builtin_amdgcn_s_sleep(1);
    }
    #pragma unroll
    for (int k = 0; k < 16; k++) {
        int i = lane + 64 * k;
        st[(i >> 7) * 129 + (i & 127)] = v[k];
    }
}
// frag read from staged slot: batch = lane&7 (cols 8-15 mirror, discarded on write)
static __device__ __forceinline__ half8 ldsfrag(const unsigned long long* __restrict__ st,
                                                int lane, int kt)
{
    int base = (lane & 7) * 129 + ((lane >> 4) << 1) + kt * 8;
    return mkfrag(st[base], st[base + 1]);
}

// ---------------- K0: convert pre_w / out_w to fp16 ----------------
__global__ __launch_bounds__(256) void k_prep(
    const float* __restrict__ pre_w, const float* __restrict__ out_w,
    unsigned short* __restrict__ prew16, unsigned short* __restrict__ outw16)
{
    int i = blockIdx.x * 256 + threadIdx.x;
    if (i < NPRE * HD) prew16[i] = f2h_bits(pre_w[i]);
    if (i < NSS * NPRE) outw16[i] = f2h_bits(out_w[i]);
}

// ---------------- K1: conv stack + linear interp (all f32) ----------------
#define CHW 218   // 200 + 2*9 halo (3 conv layers x pad 3)
__global__ __launch_bounds__(256) void k_conv(
    const float* __restrict__ xlow,
    const float* __restrict__ w0, const float* __restrict__ cb0,
    const float* __restrict__ w1, const float* __restrict__ cb1,
    const float* __restrict__ w2, const float* __restrict__ cb2,
    float* __restrict__ convout, float* __restrict__ interp)
{
    int blk = blockIdx.x; int b = blk >> 2; int ch = blk & 3; int cb = ch * 200;
    int tid = threadIdx.x;
    __shared__ float xr[224];
    __shared__ float w0l[LC * 7], w1l[LC * LC * 7], w2l[LC * LC * 7];
    __shared__ float b0l[LC], b1l[LC], b2l[LC];
    __shared__ float h0[LC][CHW], h1[LC][CHW];

    for (int i = tid; i < LC * 7; i += 256) w0l[i] = w0[i];
    for (int i = tid; i < LC * LC * 7; i += 256) { w1l[i] = w1[i]; w2l[i] = w2[i]; }
    for (int i = tid; i < LC; i += 256) { b0l[i] = cb0[i]; b1l[i] = cb1[i]; b2l[i] = cb2[i]; }
    for (int i = tid; i < 224; i += 256) {
        int g = cb - 12 + i;
        xr[i] = (g >= 0 && g < TLOW) ? xlow[b * TLOW + g] : 0.f;
    }
    __syncthreads();
    for (int i = tid; i < LC * CHW; i += 256) {
        int c = i / CHW, s = i - c * CHW;
        int tg = cb - 9 + s;
        float a = b0l[c];
        #pragma unroll
        for (int j = 0; j < 7; j++) a += w0l[c * 7 + j] * xr[s + j];
        h0[c][s] = (tg >= 0 && tg < TLOW) ? tanhf_(a) : 0.f;
    }
    __syncthreads();
    for (int i = tid; i < LC * CHW; i += 256) {
        int c = i / CHW, s = i - c * CHW;
        int tg = cb - 9 + s;
        float a = b1l[c];
        for (int ci = 0; ci < LC; ci++) {
            #pragma unroll
            for (int j = 0; j < 7; j++) {
                int ss = s + j - 3;
                float hv = (ss >= 0 && ss < CHW) ? h0[ci][ss] : 0.f;
                a += w1l[(c * LC + ci) * 7 + j] * hv;
            }
        }
        h1[c][s] = (tg >= 0 && tg < TLOW) ? tanhf_(a) : 0.f;
    }
    __syncthreads();
    for (int i = tid; i < LC * 200; i += 256) {
        int c = i / 200, t0 = i - c * 200; int s = t0 + 9;
        float a = b2l[c];
        for (int ci = 0; ci < LC; ci++) {
            #pragma unroll
            for (int j = 0; j < 7; j++) a += w2l[(c * LC + ci) * 7 + j] * h1[ci][s + j - 3];
        }
        convout[((size_t)b * TLOW + cb + t0) * LC + c] = tanhf_(a);
    }
    for (int i = tid; i < 2000; i += 256) {
        int t = cb * 10 + i;
        float src = ((float)t + 0.5f) * 0.1f - 0.5f;
        src = fminf(fmaxf(src, 0.f), (float)(TLOW - 1));
        int i0 = (int)floorf(src); int i1 = (i0 + 1 < TLOW) ? i0 + 1 : TLOW - 1;
        float w = src - (float)i0;
        interp[(size_t)b * TT + t] = xlow[b * TLOW + i0] * (1.f - w) + xlow[b * TLOW + i1] * w;
    }
}

// ---------------- K2: persistent GRU recurrence (round-6 optimum) ----------------
// grid: 64 blocks x 192 threads. blocks 0-31 = layer0 chunks, 32-63 = layer1.
// One wave polls per h-source (gate waves share the identical B-operand data),
// staged via LDS; cell over 64 lanes of wv0 in registers; u32 packed publish.
__global__ __launch_bounds__(192, 1) void k_rnn(
    const float* __restrict__ mel, const float* __restrict__ gsx,
    const float* __restrict__ convout, const float* __restrict__ interp,
    const float* __restrict__ wih0, const float* __restrict__ whh0,
    const float* __restrict__ bih0, const float* __restrict__ bhh0,
    const float* __restrict__ wih1, const float* __restrict__ whh1,
    const float* __restrict__ bih1, const float* __restrict__ bhh1,
    unsigned long long* __restrict__ h0buf, unsigned long long* __restrict__ h1buf)
{
    const int tid = threadIdx.x;
    const int wv = tid >> 6;          // 0..2 : gate (r,z,n)
    const int lane = tid & 63;
    const int lm = lane & 15, lk = lane >> 4;
    const bool isL0 = (blockIdx.x < 32);
    const int cbid = isL0 ? blockIdx.x : (blockIdx.x - 32);
    const int cb = cbid * 16;                  // h-index chunk base
    const int row = wv * 512 + cb + lm;        // gate weight row for this lane

    __shared__ float exch[3][2][16][9];        // [gate][x/h][row][batch(pad 9)]
    __shared__ __align__(16) unsigned short xvec[16][136];  // L0 input vector (fp16 bits)
    __shared__ unsigned long long stX[8 * 129]; // staged h0 slot (L1 x-part)
    __shared__ unsigned long long stH[8 * 129]; // staged edge slot (L0: h0; L1: h1)

    // cell lanes (wv0, 64 lanes): batch bb = lane>>3, rows i0=2*(lane&7), i1=i0+1
    const int cbb = lane >> 3;
    const int ci0 = (lane & 7) * 2, ci1 = ci0 + 1;
    float hr0 = 0.f, hr1 = 0.f;                // f32 recurrence state (registers)
    float bi0[3], bi1[3], bh0[3], bh1[3];
    {
        const float* bi = isL0 ? bih0 : bih1;
        const float* bh = isL0 ? bhh0 : bhh1;
        #pragma unroll
        for (int g = 0; g < 3; g++) {
            bi0[g] = bi[g * 512 + cb + ci0]; bi1[g] = bi[g * 512 + cb + ci1];
            bh0[g] = bh[g * 512 + cb + ci0]; bh1[g] = bh[g * 512 + cb + ci1];
        }
    }
    for (int i = tid; i < 16 * 136; i += 192) (&xvec[0][0])[i] = 0;

    // publish h[-1] = 0 for own chunk (slot 0): 64 u32 stores by wv0
    {
        unsigned long long* buf = isL0 ? h0buf : h1buf;
        if (wv == 0) {
            unsigned int* o32 = (unsigned int*)buf + (size_t)cbb * 256 + (cb >> 1) + (lane & 7);
            __hip_atomic_store(o32, 0u, __ATOMIC_RELAXED, __HIP_MEMORY_SCOPE_AGENT);
        }
    }

    if (isL0) {
        // weights in regs: kt 0-3 = input part (K 0..127, cols >=102 zero), kt 4-19 = whh0
        half8 wf[20];
        #pragma unroll
        for (int kt = 0; kt < 20; kt++) {
            #pragma unroll
            for (int j = 0; j < 8; j++) {
                int k = kt * 32 + lk * 8 + j;
                float v;
                if (kt < 4) v = (k < 102) ? wih0[(size_t)row * 102 + k] : 0.f;
                else        v = whh0[(size_t)row * 512 + (k - 128)];
                wf[kt][j] = (_Float16)v;
            }
        }
        // initial xvec(t=0)
        {
            float pf[5];
            #pragma unroll
            for (int u = 0; u < 5; u++) {
                int e = tid + 192 * u; float v = 0.f;
                if (e < 816) {
                    int bb = e / 102, k = e - 102 * bb;
                    if (k < 80)       v = mel[((size_t)bb * TMEL + 0) * NMEL + k];
                    else if (k < 100) v = convout[((size_t)bb * TLOW + 0) * LC + (k - 80)];
                    else if (k == 100) v = interp[(size_t)bb * TT + 0];
                    else               v = gsx[(size_t)bb * TT + 0];
                }
                pf[u] = v;
            }
            #pragma unroll
            for (int u = 0; u < 5; u++) {
                int e = tid + 192 * u;
                if (e < 816) { int bb = e / 102, k = e - 102 * bb; xvec[bb][k] = f2h_bits(pf[u]); }
            }
        }
        __syncthreads();

        for (int t = 0; t < TT; t++) {
            // prefetch x(t+1) (independent; overlaps the poll)
            int tn = (t + 1 < TT) ? (t + 1) : (TT - 1);
            int tmi = tn / 100, tli = tn / 10;
            float pf[5];
            #pragma unroll
            for (int u = 0; u < 5; u++) {
                int e = tid + 192 * u; float v = 0.f;
                if (e < 816) {
                    int bb = e / 102, k = e - 102 * bb;
                    if (k < 80)       v = mel[((size_t)bb * TMEL + tmi) * NMEL + k];
                    else if (k < 100) v = convout[((size_t)bb * TLOW + tli) * LC + (k - 80)];
                    else if (k == 100) v = interp[(size_t)bb * TT + tn];
                    else               v = gsx[(size_t)bb * TT + tn];
                }
                pf[u] = v;
            }

            if (wv == 0) poll_stage(h0buf + (size_t)t * 1024, lane, stH);
            __syncthreads();

            f32x4 accX = {0.f, 0.f, 0.f, 0.f};
            #pragma unroll
            for (int kt = 0; kt < 4; kt++) {
                half8 xf = *(const half8*)&xvec[lm][kt * 32 + lk * 8];
                accX = mfma(wf[kt], xf, accX);
            }
            f32x4 a0 = {0.f, 0.f, 0.f, 0.f}, a1 = {0.f, 0.f, 0.f, 0.f};
            #pragma unroll
            for (int i = 0; i < 8; i++) a0 = mfma(wf[4 + i], ldsfrag(stH, lane, i), a0);
            #pragma unroll
            for (int i = 0; i < 8; i++) a1 = mfma(wf[12 + i], ldsfrag(stH, lane, 8 + i), a1);
            f32x4 accH = a0 + a1;

            if (lm < 8) {
                #pragma unroll
                for (int r2 = 0; r2 < 4; r2++) {
                    exch[wv][0][lk * 4 + r2][lm] = accX[r2];
                    exch[wv][1][lk * 4 + r2][lm] = accH[r2];
                }
            }
            __syncthreads();
            if (wv == 0) {
                float Xr0 = exch[0][0][ci0][cbb], Hr0 = exch[0][1][ci0][cbb];
                float Xz0 = exch[1][0][ci0][cbb], Hz0 = exch[1][1][ci0][cbb];
                float Xn0 = exch[2][0][ci0][cbb], Hn0 = exch[2][1][ci0][cbb];
                float r0 = sigf(Xr0 + Hr0 + bi0[0] + bh0[0]);
                float z0 = sigf(Xz0 + Hz0 + bi0[1] + bh0[1]);
                float n0 = tanhf_(Xn0 + bi0[2] + r0 * (Hn0 + bh0[2]));
                hr0 = (1.f - z0) * n0 + z0 * hr0;
                float Xr1 = exch[0][0][ci1][cbb], Hr1 = exch[0][1][ci1][cbb];
                float Xz1 = exch[1][0][ci1][cbb], Hz1 = exch[1][1][ci1][cbb];
                float Xn1 = exch[2][0][ci1][cbb], Hn1 = exch[2][1][ci1][cbb];
                float r1 = sigf(Xr1 + Hr1 + bi1[0] + bh1[0]);
                float z1 = sigf(Xz1 + Hz1 + bi1[1] + bh1[1]);
                float n1 = tanhf_(Xn1 + bi1[2] + r1 * (Hn1 + bh1[2]));
                hr1 = (1.f - z1) * n1 + z1 * hr1;
                unsigned int pk = (unsigned int)f2h_bits(hr0) | ((unsigned int)f2h_bits(hr1) << 16);
                unsigned int* o32 = (unsigned int*)(h0buf + (size_t)(t + 1) * 1024)
                                  + (size_t)cbb * 256 + (cb >> 1) + (lane & 7);
                __hip_atomic_store(o32, pk, __ATOMIC_RELAXED, __HIP_MEMORY_SCOPE_AGENT);
            }
            #pragma unroll
            for (int u = 0; u < 5; u++) {
                int e = tid + 192 * u;
                if (e < 816) { int bb = e / 102, k = e - 102 * bb; xvec[bb][k] = f2h_bits(pf[u]); }
            }
            __syncthreads();
        }
    } else {
        // layer 1: K = [h0 | h1] concat (1024). kt 0-15 = wih1, kt 16-31 = whh1.
        half8 wf[32];
        #pragma unroll
        for (int kt = 0; kt < 32; kt++) {
            #pragma unroll
            for (int j = 0; j < 8; j++) {
                int k = kt * 32 + lk * 8 + j;
                float v = (kt < 16) ? wih1[(size_t)row * 512 + k]
                                    : whh1[(size_t)row * 512 + (k - 512)];
                wf[kt][j] = (_Float16)v;
            }
        }
        __syncthreads();

        for (int t = 0; t < TT; t++) {
            // parallel polls: wv0 stages h0[t] (slot t+1; L0 runs ahead),
            // wv1 stages h1[t-1] (slot t, the recurrence edge)
            if (wv == 0)      poll_stage(h0buf + (size_t)(t + 1) * 1024, lane, stX);
            else if (wv == 1) poll_stage(h1buf + (size_t)t * 1024,       lane, stH);
            __syncthreads();

            f32x4 x0 = {0.f, 0.f, 0.f, 0.f}, x1 = {0.f, 0.f, 0.f, 0.f};
            #pragma unroll
            for (int i = 0; i < 8; i++) x0 = mfma(wf[i],     ldsfrag(stX, lane, i),     x0);
            #pragma unroll
            for (int i = 0; i < 8; i++) x1 = mfma(wf[8 + i], ldsfrag(stX, lane, 8 + i), x1);
            f32x4 accX = x0 + x1;
            f32x4 a0 = {0.f, 0.f, 0.f, 0.f}, a1 = {0.f, 0.f, 0.f, 0.f};
            #pragma unroll
            for (int i = 0; i < 8; i++) a0 = mfma(wf[16 + i], ldsfrag(stH, lane, i),     a0);
            #pragma unroll
            for (int i = 0; i < 8; i++) a1 = mfma(wf[24 + i], ldsfrag(stH, lane, 8 + i), a1);
            f32x4 accH = a0 + a1;

            if (lm < 8) {
                #pragma unroll
                for (int r2 = 0; r2 < 4; r2++) {
                    exch[wv][0][lk * 4 + r2][lm] = accX[r2];
                    exch[wv][1][lk * 4 + r2][lm] = accH[r2];
                }
            }
            __syncthreads();
            if (wv == 0) {
                float Xr0 = exch[0][0][ci0][cbb], Hr0 = exch[0][1][ci0][cbb];
                float Xz0 = exch[1][0][ci0][cbb], Hz0 = exch[1][1][ci0][cbb];
                float Xn0 = exch[2][0][ci0][cbb], Hn0 = exch[2][1][ci0][cbb];
                float r0 = sigf(Xr0 + Hr0 + bi0[0] + bh0[0]);
                float z0 = sigf(Xz0 + Hz0 + bi0[1] + bh0[1]);
                float n0 = tanhf_(Xn0 + bi0[2] + r0 * (Hn0 + bh0[2]));
                hr0 = (1.f - z0) * n0 + z0 * hr0;
                float Xr1 = exch[0][0][ci1][cbb], Hr1 = exch[0][1][ci1][cbb];
                float Xz1 = exch[1][0][ci1][cbb], Hz1 = exch[1][1][ci1][cbb];
                float Xn1 = exch[2][0][ci1][cbb], Hn1 = exch[2][1][ci1][cbb];
                float r1 = sigf(Xr1 + Hr1 + bi1[0] + bh1[0]);
                float z1 = sigf(Xz1 + Hz1 + bi1[1] + bh1[1]);
                float n1 = tanhf_(Xn1 + bi1[2] + r1 * (Hn1 + bh1[2]));
                hr1 = (1.f - z1) * n1 + z1 * hr1;
                unsigned int pk = (unsigned int)f2h_bits(hr0) | ((unsigned int)f2h_bits(hr1) << 16);
                unsigned int* o32 = (unsigned int*)(h1buf + (size_t)(t + 1) * 1024)
                                  + (size_t)cbb * 256 + (cb >> 1) + (lane & 7);
                __hip_atomic_store(o32, pk, __ATOMIC_RELAXED, __HIP_MEMORY_SCOPE_AGENT);
            }
            __syncthreads();
        }
    }
}

// ---------------- K3: fused head ----------------
__global__ __launch_bounds__(256) void k_final(
    const unsigned long long* __restrict__ h1buf,
    const unsigned short* __restrict__ prew16, const float* __restrict__ pre_b,
    const unsigned short* __restrict__ outw16, const float* __restrict__ out_b,
    float* __restrict__ out)
{
    int blk = blockIdx.x; int b = blk / 125; int tb = (blk - b * 125) * 64;
    int tid = threadIdx.x; int wv = tid >> 6; int l = tid & 63;
    int lm = l & 15, lk = l >> 4;

    half8 af[16];
    int trow = tb + wv * 16 + lm;
    const unsigned long long* abase = h1buf + ((size_t)(trow + 1) * 8 + b) * 128;
    #pragma unroll
    for (int kt = 0; kt < 16; kt++)
        af[kt] = mkfrag(abase[kt * 8 + lk * 2], abase[kt * 8 + lk * 2 + 1]);

    f32x4 acc[16];
    #pragma unroll
    for (int nt = 0; nt < 16; nt++) {
        f32x4 z = {0.f, 0.f, 0.f, 0.f}; acc[nt] = z;
        #pragma unroll
        for (int kt = 0; kt < 16; kt++) {
            int n = nt * 16 + lm; int k = kt * 32 + lk * 8;
            half8 bw = *(const half8*)&prew16[(size_t)n * HD + k];
            acc[nt] = mfma(af[kt], bw, acc[nt]);
        }
    }
    __shared__ __align__(16) unsigned short pt[64][264];
    #pragma unroll
    for (int nt = 0; nt < 16; nt++) {
        float pb = pre_b[nt * 16 + lm];
        #pragma unroll
        for (int r2 = 0; r2 < 4; r2++)
            pt[wv * 16 + lk * 4 + r2][nt * 16 + lm] = f2h_bits(tanhf_(acc[nt][r2] + pb));
    }
    __syncthreads();
    f32x4 a2[2];
    { f32x4 z = {0.f, 0.f, 0.f, 0.f}; a2[0] = z; a2[1] = z; }
    #pragma unroll
    for (int kt = 0; kt < 8; kt++) {
        half8 pa = *(const half8*)&pt[wv * 16 + lm][kt * 32 + lk * 8];
        #pragma unroll
        for (int nt = 0; nt < 2; nt++) {
            int n = nt * 16 + lm;
            half8 bw = (n < NSS) ? *(const half8*)&outw16[(size_t)n * NPRE + kt * 32 + lk * 8]
                                 : mkfrag(0ull, 0ull);
            a2[nt] = mfma(pa, bw, a2[nt]);
        }
    }
    #pragma unroll
    for (int nt = 0; nt < 2; nt++) {
        int n = nt * 16 + lm;
        if (n < NSS) {
            float ob = out_b[n];
            #pragma unroll
            for (int r2 = 0; r2 < 4; r2++) {
                int t = tb + wv * 16 + lk * 4 + r2;
                out[((size_t)b * TT + t) * NSS + n] = a2[nt][r2] + ob;
            }
        }
    }
}

// ---------------- launch ----------------
extern "C" void kernel_launch(void* const* d_in, const int* in_sizes, int n_in,
                              void* d_out, int out_size, void* d_ws, size_t ws_size,
                              hipStream_t stream) {
    const float* mel  = (const float*)d_in[0];
    const float* xlow = (const float*)d_in[1];
    const float* gsx  = (const float*)d_in[2];
    const float* cw0  = (const float*)d_in[3];
    const float* cb0  = (const float*)d_in[4];
    const float* cw1  = (const float*)d_in[5];
    const float* cb1  = (const float*)d_in[6];
    const float* cw2  = (const float*)d_in[7];
    const float* cb2  = (const float*)d_in[8];
    const float* wih0 = (const float*)d_in[9];
    const float* whh0 = (const float*)d_in[10];
    const float* bih0 = (const float*)d_in[11];
    const float* bhh0 = (const float*)d_in[12];
    const float* wih1 = (const float*)d_in[13];
    const float* whh1 = (const float*)d_in[14];
    const float* bih1 = (const float*)d_in[15];
    const float* bhh1 = (const float*)d_in[16];
    const float* prew = (const float*)d_in[17];
    const float* preb = (const float*)d_in[18];
    const float* outw = (const float*)d_in[19];
    const float* outb = (const float*)d_in[20];

    size_t needed = 2 * HB_BYTES + CONV_BYTES + INTERP_BYTES + PREW16_BYTES + OUTW16_BYTES;
    if (ws_size < needed) return;

    char* ws = (char*)d_ws;
    unsigned long long* h0buf = (unsigned long long*)ws;
    unsigned long long* h1buf = (unsigned long long*)(ws + HB_BYTES);
    float* convout = (float*)(ws + 2 * HB_BYTES);
    float* interp  = (float*)(ws + 2 * HB_BYTES + CONV_BYTES);
    unsigned short* prew16 = (unsigned short*)(ws + 2 * HB_BYTES + CONV_BYTES + INTERP_BYTES);
    unsigned short* outw16 = (unsigned short*)(ws + 2 * HB_BYTES + CONV_BYTES + INTERP_BYTES + PREW16_BYTES);

    // sentinel-init both h broadcast buffers (0xFF.. = NaN fp16 pairs / 0xFFFFFFFF u32 sentinel)
    hipMemsetAsync(ws, 0xFF, 2 * HB_BYTES, stream);

    k_prep<<<(NPRE * HD + 255) / 256, 256, 0, stream>>>(prew, outw, prew16, outw16);
    k_conv<<<32, 256, 0, stream>>>(xlow, cw0, cb0, cw1, cb1, cw2, cb2, convout, interp);
    k_rnn<<<64, 192, 0, stream>>>(mel, gsx, convout, interp,
                                  wih0, whh0, bih0, bhh0,
                                  wih1, whh1, bih1, bhh1,
                                  h0buf, h1buf);
    k_final<<<1000, 256, 0, stream>>>(h1buf, prew16, preb, outw16, outb, (float*)d_out);
}